// Round 4
// baseline (94.227 us; speedup 1.0000x reference)
//
#include <hip/hip_runtime.h>
#include <hip/hip_bf16.h>

#define SEQ_L 512
#define EDIM 300
#define HDIM 512
#define ODIM 5
#define BATCH 1024
#define NCH 4
#define CPOS (SEQ_L / NCH)      // 128 interleaved positions per chunk
#define NEMB (BATCH * NCH)      // 4096 embed blocks
#define TCOLS 10                // ceil(300/32)
#define TROWS 16                // 512/32
#define NTRN (TCOLS * TROWS)    // 160 transpose tiles
#define RB 4

typedef float floatx4 __attribute__((ext_vector_type(4)));

__device__ __forceinline__ floatx4 ldnt4(const float* p) {
  return __builtin_nontemporal_load(reinterpret_cast<const floatx4*>(p));
}
__device__ __forceinline__ float ldnt1(const float* p) {
  return __builtin_nontemporal_load(p);
}

// ---------------- Kernel 1: fused embed-gather + w1-transpose + out-init ----
// Blocks [0, NEMB): interleaved-chunk embedding partial sums (as round 3).
// Blocks [NEMB, NEMB+NTRN): transpose w1 [512,300] -> w1t [300,512].
// Block NEMB+NTRN: init out = b2 (consumed by mlp's atomicAdd).
// The aux blocks ride behind the gather blocks for free.
__global__ __launch_bounds__(256, 8) void fused_embed_kernel(
    const int* __restrict__ x, const float* __restrict__ weight,
    const float* __restrict__ w1, const float* __restrict__ b2,
    float* __restrict__ part, int* __restrict__ cnt,
    float* __restrict__ w1t, float* __restrict__ out) {
  const int blk = blockIdx.x;
  const int tid = threadIdx.x;

  if (blk >= NEMB) {
    const int aux = blk - NEMB;
    if (aux < NTRN) {
      __shared__ float tile[32][33];
      const int tc = aux % TCOLS, tr = aux / TCOLS;
      const int c0 = tc * 32, r0 = tr * 32;
      const int tx = tid & 31, ty = tid >> 5;
#pragma unroll
      for (int i = 0; i < 4; ++i) {
        const int r = r0 + ty + i * 8, c = c0 + tx;
        if (c < EDIM) tile[ty + i * 8][tx] = w1[r * EDIM + c];
      }
      __syncthreads();
#pragma unroll
      for (int i = 0; i < 4; ++i) {
        const int c = c0 + ty + i * 8, r = r0 + tx;
        if (c < EDIM) w1t[c * HDIM + r] = tile[tx][ty + i * 8];
      }
    } else {
      for (int i = tid; i < BATCH * ODIM; i += 256) out[i] = b2[i % ODIM];
    }
    return;
  }

  // ---- embed path ----
  const int b = blk >> 2;
  const int c = blk & 3;
  __shared__ int stok[CPOS];
  __shared__ int s_nz;
  __shared__ float sred[4][304];

  if (tid == 0) s_nz = 0;
  __syncthreads();

  int tok = 0;
  if (tid < CPOS) {
    tok = x[b * SEQ_L + c + NCH * tid];
    stok[tid] = tok;
  }
  const unsigned long long nzmask = __ballot(tid < CPOS && tok != 0);
  if (tid < CPOS && (tid & 63) == 0) atomicAdd(&s_nz, __popcll(nzmask));
  __syncthreads();
  const int n_c = s_nz;  // nonzero count (prefix in i) of this chunk

  const int wave = tid >> 6;
  const int lane = tid & 63;
  const bool hasS = lane < (EDIM - 256);  // lanes 0..43 own float 256+lane

  floatx4 acc = {0.f, 0.f, 0.f, 0.f};
  float accS = 0.f;

  int i = wave;
  for (; i + 20 < n_c; i += 24) {  // waves stride 4; window = 6 tokens
    const float* r0 = weight + (size_t)stok[i] * EDIM;
    const float* r1 = weight + (size_t)stok[i + 4] * EDIM;
    const float* r2 = weight + (size_t)stok[i + 8] * EDIM;
    const float* r3 = weight + (size_t)stok[i + 12] * EDIM;
    const float* r4 = weight + (size_t)stok[i + 16] * EDIM;
    const float* r5 = weight + (size_t)stok[i + 20] * EDIM;
    const floatx4 v0 = ldnt4(r0 + 4 * lane);
    const floatx4 v1 = ldnt4(r1 + 4 * lane);
    const floatx4 v2 = ldnt4(r2 + 4 * lane);
    const floatx4 v3 = ldnt4(r3 + 4 * lane);
    const floatx4 v4 = ldnt4(r4 + 4 * lane);
    const floatx4 v5 = ldnt4(r5 + 4 * lane);
    float s0 = 0.f, s1 = 0.f, s2 = 0.f, s3 = 0.f, s4 = 0.f, s5 = 0.f;
    if (hasS) {
      s0 = ldnt1(r0 + 256 + lane); s1 = ldnt1(r1 + 256 + lane);
      s2 = ldnt1(r2 + 256 + lane); s3 = ldnt1(r3 + 256 + lane);
      s4 = ldnt1(r4 + 256 + lane); s5 = ldnt1(r5 + 256 + lane);
    }
    acc += (v0 + v1) + (v2 + v3) + (v4 + v5);
    accS += (s0 + s1) + (s2 + s3) + (s4 + s5);
  }
  for (; i < n_c; i += 4) {
    const float* r = weight + (size_t)stok[i] * EDIM;
    const floatx4 v = ldnt4(r + 4 * lane);
    acc += v;
    if (hasS) accS += ldnt1(r + 256 + lane);
  }

  *reinterpret_cast<floatx4*>(&sred[wave][4 * lane]) = acc;
  if (hasS) sred[wave][256 + lane] = accS;
  __syncthreads();

  for (int d = tid; d < EDIM; d += 256) {
    part[(size_t)blk * EDIM + d] =
        sred[0][d] + sred[1][d] + sred[2][d] + sred[3][d];
  }
  if (tid == 0) cnt[blk] = n_c;
}

// ---------------- Kernel 2: fused reduce + MLP + atomic out -----------------
// 512 blocks = 256 row-groups (RB=4) x 2 hidden-halves. Thread owns one
// hidden unit of its half; relu(h) reduced per-wave into out via atomicAdd
// (out pre-initialized to b2 by kernel 1).
__global__ __launch_bounds__(256) void mlp_kernel(
    const float* __restrict__ part, const int* __restrict__ cnt,
    const float* __restrict__ w0,  // weight row 0 (padding embedding)
    const float* __restrict__ w1t, const float* __restrict__ b1,
    const float* __restrict__ w2, float* __restrict__ out) {
  const int rg = blockIdx.x >> 1;
  const int hh = blockIdx.x & 1;
  const int b0 = rg * RB;
  const int j0 = hh * 256;
  __shared__ float sy[RB][304];
  __shared__ float sh[RB][256];
  __shared__ float slen[RB];

  const int tid = threadIdx.x;
  if (tid < RB) {
    const int* cb = cnt + (b0 + tid) * NCH;
    slen[tid] = (float)(cb[0] + cb[1] + cb[2] + cb[3]);  // len >= 1
  }
  __syncthreads();

  for (int i = tid; i < RB * EDIM; i += 256) {
    const int r = i / EDIM, d = i - r * EDIM;
    const float* pb = part + (size_t)(b0 + r) * NCH * EDIM;
    float s = (pb[d] + pb[EDIM + d]) + (pb[2 * EDIM + d] + pb[3 * EDIM + d]);
    const float len = slen[r];
    s += ((float)SEQ_L - len) * w0[d];
    sy[r][d] = s / len;
  }
  __syncthreads();

  float acc[RB];
#pragma unroll
  for (int r = 0; r < RB; ++r) acc[r] = 0.f;

  const float* wcol = w1t + j0 + tid;
#pragma unroll 4
  for (int k = 0; k < EDIM; ++k) {
    const float wv = wcol[(size_t)k * HDIM];
#pragma unroll
    for (int r = 0; r < RB; ++r) acc[r] = fmaf(wv, sy[r][k], acc[r]);
  }

  const float bb = b1[j0 + tid];
#pragma unroll
  for (int r = 0; r < RB; ++r) sh[r][tid] = fmaxf(acc[r] + bb, 0.f);
  __syncthreads();

  const int wave = tid >> 6;
  const int lane = tid & 63;
  if (wave < RB) {
    const int rr = wave;
#pragma unroll
    for (int o = 0; o < ODIM; ++o) {
      float p = 0.f;
#pragma unroll
      for (int jj = 0; jj < 4; ++jj) {
        const int j = lane + jj * 64;
        p = fmaf(w2[o * HDIM + j0 + j], sh[rr][j], p);
      }
#pragma unroll
      for (int off = 32; off > 0; off >>= 1) p += __shfl_down(p, off);
      if (lane == 0) atomicAdd(&out[(size_t)(b0 + rr) * ODIM + o], p);
    }
  }
}

extern "C" void kernel_launch(void* const* d_in, const int* in_sizes, int n_in,
                              void* d_out, int out_size, void* d_ws, size_t ws_size,
                              hipStream_t stream) {
  const int* x = (const int*)d_in[0];          // [1024, 512] int32
  const float* weight = (const float*)d_in[1]; // [100000, 300]
  const float* w1 = (const float*)d_in[2];     // [512, 300]
  const float* b1 = (const float*)d_in[3];     // [512]
  const float* w2 = (const float*)d_in[4];     // [5, 512]
  const float* b2 = (const float*)d_in[5];     // [5]
  float* out = (float*)d_out;                  // [1024, 5]

  // ws layout: part [4096*300] f32 | w1t [300*512] f32 | cnt [4096] i32
  float* part = (float*)d_ws;
  float* w1t = part + (size_t)BATCH * NCH * EDIM;
  int* cnt = (int*)(w1t + (size_t)EDIM * HDIM);

  fused_embed_kernel<<<NEMB + NTRN + 1, 256, 0, stream>>>(
      x, weight, w1, b2, part, cnt, w1t, out);

  mlp_kernel<<<(BATCH / RB) * 2, 256, 0, stream>>>(part, cnt, weight, w1t, b1,
                                                   w2, out);
}